// Round 3
// baseline (262.966 us; speedup 1.0000x reference)
//
#include <hip/hip_runtime.h>
#include <hip/hip_bf16.h>

// RadarSecondStageGenerator — fused single kernel, fp32 I/O.
//
// Because h0 == 0 in the reference, the flow generator / warp / w_ret branch is
// dead (warping a zero image yields zero; h2h reduces to b_ret). The network
// collapses to: conv3x3(24->8) -> conv3x3(8->24) -> GRU gates (h2h == b_ret)
// -> conv1x1(8->12).
//
// One block = one 16x16 spatial tile of one batch element.
//   Phase 1: stage 20x20x24 input patch (halo 2, zero-padded) into LDS.
//   Phase 2: conv_in -> 18x18x8 "x" tile in LDS. CRITICAL: x-halo positions
//            outside [0,128)^2 must be ZERO (the reference zero-pads x for the
//            i2h conv; it does NOT evaluate conv_in outside the image).
//   Phase 3: conv_i2h (3x3, 8->24) + sigmoid/leaky gate math + conv1x1 (8->12).
// Weights indexed wave-uniformly -> scalar loads (SGPR operand into v_fmac).

#define TILE 16
#define HW 128

__global__ __launch_bounds__(256)
void radar2_fused(const float* __restrict__ radar,   // (32,12,128,128)
                  const float* __restrict__ pred,    // (32,12,128,128)
                  const float* __restrict__ w_in,    // (8,24,3,3)
                  const float* __restrict__ b_in,    // (8)
                  const float* __restrict__ w_i2h,   // (24,8,3,3)
                  const float* __restrict__ b_i2h,   // (24)
                  const float* __restrict__ b_ret,   // (24)
                  const float* __restrict__ w_out,   // (12,8)
                  const float* __restrict__ b_out,   // (12)
                  float* __restrict__ out)           // (32,12,128,128)
{
    __shared__ float s_in[24 * 20 * 20];   // [c][ly][lx], halo 2
    __shared__ float s_x[8 * 18 * 18];     // [m][py][px], halo 1

    const int tid = threadIdx.x;
    const int b   = blockIdx.z;
    const int ty0 = blockIdx.y * TILE;
    const int tx0 = blockIdx.x * TILE;

    // ---- Phase 1: global -> LDS input patch (zero-padded) ----
    for (int idx = tid; idx < 24 * 400; idx += 256) {
        int c   = idx / 400;
        int rem = idx - c * 400;
        int ly  = rem / 20;
        int lx  = rem - ly * 20;
        int gy  = ty0 + ly - 2;
        int gx  = tx0 + lx - 2;
        float v = 0.0f;
        if ((unsigned)gy < (unsigned)HW && (unsigned)gx < (unsigned)HW) {
            const float* src = (c < 12)
                ? (radar + (((size_t)b * 12 + c) << 14))
                : (pred  + (((size_t)b * 12 + (c - 12)) << 14));
            v = src[(gy << 7) + gx];
        }
        s_in[idx] = v;
    }
    __syncthreads();

    // ---- Phase 2: conv_in (24 -> 8, 3x3) on 18x18 halo tile ----
    // s_x[py][px] holds x at global (ty0+py-1, tx0+px-1); zero outside image.
    for (int p = tid; p < 18 * 18; p += 256) {
        int py = p / 18;
        int px = p - py * 18;
        int gy = ty0 + py - 1;
        int gx = tx0 + px - 1;
        if ((unsigned)gy >= (unsigned)HW || (unsigned)gx >= (unsigned)HW) {
#pragma unroll
            for (int oc = 0; oc < 8; ++oc) s_x[oc * 324 + p] = 0.0f;
            continue;
        }
        float acc[8];
#pragma unroll
        for (int oc = 0; oc < 8; ++oc) acc[oc] = b_in[oc];
        for (int c = 0; c < 24; ++c) {
            const float* wc = w_in + c * 9;   // + oc*216 + dy*3 + dx
            const float* ic = s_in + c * 400 + py * 20 + px;
#pragma unroll
            for (int dy = 0; dy < 3; ++dy) {
#pragma unroll
                for (int dx = 0; dx < 3; ++dx) {
                    float v = ic[dy * 20 + dx];
#pragma unroll
                    for (int oc = 0; oc < 8; ++oc)
                        acc[oc] = fmaf(v, wc[oc * 216 + dy * 3 + dx], acc[oc]);
                }
            }
        }
#pragma unroll
        for (int oc = 0; oc < 8; ++oc) s_x[oc * 324 + p] = acc[oc];
    }
    __syncthreads();

    // ---- Phase 3: conv_i2h (8 -> 24, 3x3) + gates + conv_out (1x1, 8 -> 12) ----
    const int oy = tid >> 4;
    const int ox = tid & 15;

    float acc[24];
#pragma unroll
    for (int o = 0; o < 24; ++o) acc[o] = b_i2h[o];
    for (int m = 0; m < 8; ++m) {
        const float* xm = s_x + m * 324 + oy * 18 + ox;
        const float* wm = w_i2h + m * 9;   // + o*72 + dy*3 + dx
#pragma unroll
        for (int dy = 0; dy < 3; ++dy) {
#pragma unroll
            for (int dx = 0; dx < 3; ++dx) {
                float v = xm[dy * 18 + dx];
#pragma unroll
                for (int o = 0; o < 24; ++o)
                    acc[o] = fmaf(v, wm[o * 72 + dy * 3 + dx], acc[o]);
            }
        }
    }

    float hcell[8];
#pragma unroll
    for (int c = 0; c < 8; ++c) {
        float r = 1.0f / (1.0f + __expf(-(acc[c]      + b_ret[c])));
        float u = 1.0f / (1.0f + __expf(-(acc[8 + c]  + b_ret[8 + c])));
        float mm = acc[16 + c] + r * b_ret[16 + c];
        mm = (mm >= 0.0f) ? mm : 0.2f * mm;
        hcell[c] = (1.0f - u) * mm;
    }

    const int gy = ty0 + oy;
    const int gx = tx0 + ox;
    float* op = out + (((size_t)b * 12) << 14) + (gy << 7) + gx;
#pragma unroll
    for (int t = 0; t < 12; ++t) {
        float o = b_out[t];
#pragma unroll
        for (int c = 0; c < 8; ++c)
            o = fmaf(hcell[c], w_out[t * 8 + c], o);
        op[(size_t)t << 14] = o;
    }
}

extern "C" void kernel_launch(void* const* d_in, const int* in_sizes, int n_in,
                              void* d_out, int out_size, void* d_ws, size_t ws_size,
                              hipStream_t stream) {
    (void)in_sizes; (void)n_in; (void)d_ws; (void)ws_size; (void)out_size;
    const float* radar  = (const float*)d_in[0];
    const float* pred   = (const float*)d_in[1];
    const float* w_in   = (const float*)d_in[2];
    const float* b_in   = (const float*)d_in[3];
    const float* w_i2h  = (const float*)d_in[4];
    const float* b_i2h  = (const float*)d_in[5];
    // d_in[6..12] (flow branch, w_ret) are dead: h0 == 0.
    const float* b_ret  = (const float*)d_in[13];
    const float* w_out  = (const float*)d_in[14];
    const float* b_out  = (const float*)d_in[15];
    float* out = (float*)d_out;

    dim3 grid(HW / TILE, HW / TILE, 32);
    radar2_fused<<<grid, dim3(256), 0, stream>>>(radar, pred, w_in, b_in,
                                                 w_i2h, b_i2h, b_ret,
                                                 w_out, b_out, out);
}

// Round 4
// 182.897 us; speedup vs baseline: 1.4378x; 1.4378x over previous
//
#include <hip/hip_runtime.h>
#include <hip/hip_bf16.h>

// RadarSecondStageGenerator — fused, fp32, instruction-diet version.
//
// h0 == 0 ⇒ flow/warp/w_ret branch dead; network = conv3x3(24->8) ->
// conv3x3(8->24) -> GRU gates (h2h == b_ret) -> conv1x1(8->12).
//
// Round-4 changes vs round 3 (which passed at 190 µs, VALUBusy 41%, occ 31%):
//  * channel-last LDS: s_in[pos][12], s_x[pos][8] -> ds_read_b128 (3 or 2 per
//    tap) instead of per-channel ds_read_b32; stride-12 lanes are conflict-free.
//  * weights pre-transposed into d_ws by a prep kernel so inner loops read them
//    contiguously -> s_load_dwordx16 bursts (SGPR operand into v_fmac).
//  * input staged in two 12-channel chunks -> LDS 29.6 KB -> 5 blocks/CU.

#define HW 128

// ---- d_ws float layout ----
// wA  [ch2][pos9][cc12][oc8] @ 0     (1728)   conv_in weights, transposed
// wB  [pos9][m8][o24]        @ 1728  (1728)   i2h weights, transposed
// bin @3456(8)  bi2h @3464(24)  bret @3488(24)  wout @3512(96)  bout @3608(12)
#define N_WS 3620

__global__ __launch_bounds__(256)
void prep_weights(const float* __restrict__ w_in,  const float* __restrict__ b_in,
                  const float* __restrict__ w_i2h, const float* __restrict__ b_i2h,
                  const float* __restrict__ b_ret, const float* __restrict__ w_out,
                  const float* __restrict__ b_out, float* __restrict__ ws)
{
    int i = blockIdx.x * 256 + threadIdx.x;
    if (i >= N_WS) return;
    float v;
    if (i < 1728) {                       // wA[ch][pos][cc][oc] <- w_in[oc][ch*12+cc][pos]
        int oc = i & 7;  int t = i >> 3;  // t = (ch*9+pos)*12 + cc
        int cc = t % 12; t /= 12;         // t = ch*9 + pos
        int pos = t % 9; int ch = t / 9;
        v = w_in[oc * 216 + (ch * 12 + cc) * 9 + pos];
    } else if (i < 3456) {                // wB[pos][m][o] <- w_i2h[o][m][pos]
        int j = i - 1728;
        int o = j % 24;  int t = j / 24;  // t = pos*8 + m
        int m = t & 7;   int pos = t >> 3;
        v = w_i2h[o * 72 + m * 9 + pos];
    }
    else if (i < 3464) v = b_in [i - 3456];
    else if (i < 3488) v = b_i2h[i - 3464];
    else if (i < 3512) v = b_ret[i - 3488];
    else if (i < 3608) v = w_out[i - 3512];
    else               v = b_out[i - 3608];
    ws[i] = v;
}

// conv_in accumulate for one x-halo pixel: 9 taps x 12ch x 8oc
__device__ __forceinline__ void conv_in_px(float a[8], const float* __restrict__ sb,
                                           const float* __restrict__ wAc)
{
#pragma unroll 1
    for (int dy = 0; dy < 3; ++dy) {
        const float* srow = sb  + dy * 240;   // (dy*20)*12
        const float* wrow = wAc + dy * 288;   // (dy*3)*96
#pragma unroll
        for (int dx = 0; dx < 3; ++dx) {
            const float* sp = srow + dx * 12;
            float4 t0 = *(const float4*)(sp);
            float4 t1 = *(const float4*)(sp + 4);
            float4 t2 = *(const float4*)(sp + 8);
            float v[12] = {t0.x, t0.y, t0.z, t0.w,
                           t1.x, t1.y, t1.z, t1.w,
                           t2.x, t2.y, t2.z, t2.w};
            const float* wp = wrow + dx * 96;   // [cc][oc]
#pragma unroll
            for (int cc = 0; cc < 12; ++cc)
#pragma unroll
                for (int oc = 0; oc < 8; ++oc)
                    a[oc] = fmaf(v[cc], wp[cc * 8 + oc], a[oc]);
        }
    }
}

__global__ __launch_bounds__(256, 5)
void radar2_fused(const float* __restrict__ radar,   // (32,12,128,128)
                  const float* __restrict__ pred,    // (32,12,128,128)
                  const float* __restrict__ ws,
                  float* __restrict__ out)           // (32,12,128,128)
{
    __shared__ float s_in[400 * 12];   // [ly*20+lx][cc], halo-2 patch, one chunk
    __shared__ float s_x [324 * 8];    // [py*18+px][m],  x halo-1 tile

    const float* bin  = ws + 3456;
    const float* bi2h = ws + 3464;
    const float* bret = ws + 3488;
    const float* wout = ws + 3512;
    const float* bout = ws + 3608;

    const int tid = threadIdx.x;
    const int b   = blockIdx.z;
    const int ty0 = blockIdx.y * 16;
    const int tx0 = blockIdx.x * 16;

    // each thread owns x-halo pixels p0 and (maybe) p1 on the 18x18 grid
    const int p0 = tid;
    const int p1 = tid + 256;
    const bool p1ok = (p1 < 324);
    const int py0 = p0 / 18, px0 = p0 - 18 * py0;
    const int py1 = p1 / 18, px1 = p1 - 18 * py1;
    const bool v0 = ((unsigned)(ty0 + py0 - 1) < (unsigned)HW) &
                    ((unsigned)(tx0 + px0 - 1) < (unsigned)HW);
    const bool v1 = p1ok & ((unsigned)(ty0 + py1 - 1) < (unsigned)HW) &
                           ((unsigned)(tx0 + px1 - 1) < (unsigned)HW);

    float a0[8], a1[8];
#pragma unroll
    for (int oc = 0; oc < 8; ++oc) { a0[oc] = bin[oc]; a1[oc] = bin[oc]; }

#pragma unroll 1
    for (int ch = 0; ch < 2; ++ch) {
        __syncthreads();   // previous chunk's reads done before overwrite
        // ---- stage 12 channels of the 20x20 halo-2 patch, channel-last ----
        const float* src = (ch == 0 ? radar : pred) + (((size_t)b * 12) << 14);
#pragma unroll 1
        for (int r = tid; r < 400; r += 256) {
            const int ly = r / 20, lx = r - 20 * ly;
            const int gy = ty0 + ly - 2, gx = tx0 + lx - 2;
            const bool in = ((unsigned)gy < (unsigned)HW) & ((unsigned)gx < (unsigned)HW);
            const float* sp = src + (gy << 7) + gx;
            float* dp = s_in + r * 12;
#pragma unroll
            for (int c = 0; c < 12; ++c)
                dp[c] = in ? sp[(size_t)c << 14] : 0.0f;
        }
        __syncthreads();

        const float* wAc = ws + ch * 864;
        conv_in_px(a0, s_in + (py0 * 20 + px0) * 12, wAc);
        if (p1ok)
            conv_in_px(a1, s_in + (py1 * 20 + px1) * 12, wAc);
    }

    // ---- write x tile (zero outside the image: reference zero-pads x) ----
    {
        float* xp = s_x + p0 * 8;
#pragma unroll
        for (int oc = 0; oc < 8; ++oc) xp[oc] = v0 ? a0[oc] : 0.0f;
    }
    if (p1ok) {
        float* xp = s_x + p1 * 8;
#pragma unroll
        for (int oc = 0; oc < 8; ++oc) xp[oc] = v1 ? a1[oc] : 0.0f;
    }
    __syncthreads();

    // ---- conv_i2h (3x3, 8->24) + gates + conv_out (1x1, 8->12) ----
    const int oy = tid >> 4, ox = tid & 15;
    float acc[24];
#pragma unroll
    for (int o = 0; o < 24; ++o) acc[o] = bi2h[o];

    const float* wB = ws + 1728;
#pragma unroll 1
    for (int dy = 0; dy < 3; ++dy) {
        const float* xrow = s_x + ((oy + dy) * 18 + ox) * 8;
        const float* wrow = wB + dy * 576;   // (dy*3)*192
#pragma unroll
        for (int dx = 0; dx < 3; ++dx) {
            float4 x0 = *(const float4*)(xrow + dx * 8);
            float4 x1 = *(const float4*)(xrow + dx * 8 + 4);
            float xv[8] = {x0.x, x0.y, x0.z, x0.w, x1.x, x1.y, x1.z, x1.w};
            const float* wp = wrow + dx * 192;   // [m][o]
#pragma unroll
            for (int m = 0; m < 8; ++m)
#pragma unroll
                for (int o = 0; o < 24; ++o)
                    acc[o] = fmaf(xv[m], wp[m * 24 + o], acc[o]);
        }
    }

    float hcell[8];
#pragma unroll
    for (int c = 0; c < 8; ++c) {
        float r = 1.0f / (1.0f + __expf(-(acc[c]     + bret[c])));
        float u = 1.0f / (1.0f + __expf(-(acc[8 + c] + bret[8 + c])));
        float mm = acc[16 + c] + r * bret[16 + c];
        mm = (mm >= 0.0f) ? mm : 0.2f * mm;
        hcell[c] = (1.0f - u) * mm;
    }

    const int gy = ty0 + oy, gx = tx0 + ox;
    float* op = out + (((size_t)b * 12) << 14) + (gy << 7) + gx;
#pragma unroll
    for (int t = 0; t < 12; ++t) {
        float o = bout[t];
#pragma unroll
        for (int c = 0; c < 8; ++c)
            o = fmaf(hcell[c], wout[t * 8 + c], o);
        op[(size_t)t << 14] = o;
    }
}

extern "C" void kernel_launch(void* const* d_in, const int* in_sizes, int n_in,
                              void* d_out, int out_size, void* d_ws, size_t ws_size,
                              hipStream_t stream) {
    (void)in_sizes; (void)n_in; (void)ws_size; (void)out_size;
    const float* radar = (const float*)d_in[0];
    const float* pred  = (const float*)d_in[1];
    const float* w_in  = (const float*)d_in[2];
    const float* b_in  = (const float*)d_in[3];
    const float* w_i2h = (const float*)d_in[4];
    const float* b_i2h = (const float*)d_in[5];
    // d_in[6..12] (flow branch, w_ret) are dead: h0 == 0.
    const float* b_ret = (const float*)d_in[13];
    const float* w_out = (const float*)d_in[14];
    const float* b_out = (const float*)d_in[15];
    float* ws  = (float*)d_ws;
    float* out = (float*)d_out;

    prep_weights<<<(N_WS + 255) / 256, 256, 0, stream>>>(w_in, b_in, w_i2h, b_i2h,
                                                         b_ret, w_out, b_out, ws);

    dim3 grid(HW / 16, HW / 16, 32);
    radar2_fused<<<grid, dim3(256), 0, stream>>>(radar, pred, ws, out);
}

// Round 5
// 146.787 us; speedup vs baseline: 1.7915x; 1.2460x over previous
//
#include <hip/hip_runtime.h>
#include <hip/hip_bf16.h>

// RadarSecondStageGenerator — MFMA (fp16 in, fp32 acc) fully-fused version.
//
// h0 == 0 ⇒ flow/warp/w_ret branch dead; network = conv3x3(24->8) ->
// conv3x3(8->24) -> GRU gates (h2h == b_ret) -> conv1x1(8->12).
//
// Both convs run as im2col GEMMs on v_mfma_f32_16x16x32_f16:
//  conv_in: M = 324 x-halo px (21 tiles), N = 8(+8 pad), K = 2 chunks x 5
//           MFMA-steps of (2 taps x 16 ch); bias folded via a constant-1
//           channel (chunk1 ch12) active only at the center tap's weight.
//  i2h:     M = 256 px (16 tiles), N = 24 (2 N-tiles), K = 12 taps x 8 ch
//           (3 MFMA-steps); s_x is channel-last [px][8] fp16 so a lane's
//           A-fragment is one contiguous 16B ds_read_b128.
// Gates computed straight from C-fragments: i_u lives 8 lanes away -> shfl_xor.
// Fragment layouts per verified guide: A[m=lane&15][k=quad*8+j],
// C[row=quad*4+reg][col=lane&15].

typedef _Float16 v8h __attribute__((ext_vector_type(8)));
typedef float    v4f __attribute__((ext_vector_type(4)));

#define HW 128

// ---- ws byte layout ----
#define WAF_OFF 0        // conv_in B-frags: [ch2][step5][lane64][j8] f16 = 10240 B
#define WBF_OFF 10240    // i2h B-frags: [step3][nt2][lane64][j8] f16 = 6144 B
#define FLT_OFF 16384    // floats: g0..g3[32], wout[96]@32, bout[12]@128
#define N_PREP  (8192 + 140)

__global__ __launch_bounds__(256)
void prep(const float* __restrict__ w_in,  const float* __restrict__ b_in,
          const float* __restrict__ w_i2h, const float* __restrict__ b_i2h,
          const float* __restrict__ b_ret, const float* __restrict__ w_out,
          const float* __restrict__ b_out, void* __restrict__ ws)
{
    int idx = blockIdx.x * 256 + threadIdx.x;
    _Float16* wh = (_Float16*)ws;
    float* fw = (float*)((char*)ws + FLT_OFF);
    if (idx < 5120) {                       // conv_in B-frag pack
        int j = idx & 7, r = idx >> 3;
        int lane = r & 63; r >>= 6;
        int s = r % 5, ch = r / 5;
        int quad = lane >> 4, n = lane & 15;
        int k = quad * 8 + j;
        int tl = k >> 4, ci = k & 15;
        int t = s * 2 + tl;                 // tap 0..9 (9 = pad)
        float v = 0.f;
        if (n < 8) {
            if (ci < 12 && t < 9)            v = w_in[n*216 + (ch*12+ci)*9 + t];
            else if (ch==1 && ci==12 && t==4) v = b_in[n];   // bias via ones-ch
        }
        wh[idx] = (_Float16)v;
    } else if (idx < 8192) {                // i2h B-frag pack
        int i2 = idx - 5120;
        int j = i2 & 7, r = i2 >> 3;
        int lane = r & 63; r >>= 6;
        int nt = r & 1, s = r >> 1;
        int quad = lane >> 4, n = lane & 15;
        int kk = s * 32 + quad * 8 + j;     // K order: tap-major, 8ch per tap
        int t = kk >> 3, m = kk & 7;        // tap 0..11 (9..11 pad)
        int o = nt * 16 + n;
        float v = (t < 9 && o < 24) ? w_i2h[o*72 + m*9 + t] : 0.f;
        wh[WBF_OFF/2 + i2] = (_Float16)v;
    } else if (idx < N_PREP) {
        int j = idx - 8192;
        float v;
        if (j < 32) {                       // combined gate biases
            int c = j & 7, sel = j >> 3;
            v = (sel==0) ? b_i2h[c]    + b_ret[c]
              : (sel==1) ? b_i2h[8+c]  + b_ret[8+c]
              : (sel==2) ? b_i2h[16+c] : b_ret[16+c];
        } else if (j < 128) v = w_out[j-32];
        else                v = b_out[j-128];
        fw[j] = v;
    }
}

__global__ __launch_bounds__(256, 4)
void radar2_mfma(const float* __restrict__ radar,  // (32,12,128,128)
                 const float* __restrict__ pred,   // (32,12,128,128)
                 const void*  __restrict__ ws,
                 float* __restrict__ out)          // (32,12,128,128)
{
    __shared__ _Float16 s_in[400 * 16];   // [pos 20x20][16ch] one 12-ch chunk
    __shared__ _Float16 s_x [336 * 8];    // [x-halo px][8ch]
    __shared__ float    s_hc[256 * 9];    // [px][8ch + pad] hcell

    const _Float16* wh = (const _Float16*)ws;
    const float* fw = (const float*)((const char*)ws + FLT_OFF);

    const int tid  = threadIdx.x;
    const int lane = tid & 63;
    const int wave = tid >> 6;
    const int quad = lane >> 4;
    const int col  = lane & 15;
    const int b   = blockIdx.z;
    const int ty0 = blockIdx.y * 16;
    const int tx0 = blockIdx.x * 16;

    // ---- per-lane conv_in A addressing (6 possible M-tiles per wave) ----
    int pbase[6];
#pragma unroll
    for (int t = 0; t < 6; ++t) {
        int mt = wave + 4 * t;
        int p = mt * 16 + col; if (p > 323) p = 323;      // clamp garbage rows
        pbase[t] = ((p / 18) * 20 + (p % 18)) * 16 + (quad & 1) * 8;
    }
    int toff1[5];
#pragma unroll
    for (int s = 0; s < 5; ++s) {
        int tq = s * 2 + (quad >> 1);
        toff1[s] = (tq < 9) ? ((tq / 3) * 20 + (tq % 3)) * 16 : 0;
    }

    v4f accA[6];
#pragma unroll
    for (int t = 0; t < 6; ++t) accA[t] = (v4f){0.f, 0.f, 0.f, 0.f};

    // ---- conv_in: 2 chunks of 12 channels ----
    for (int ch = 0; ch < 2; ++ch) {
        __syncthreads();
        const float* src = (ch ? pred : radar) + (((size_t)b * 12) << 14);
        for (int r = tid; r < 400; r += 256) {
            int ly = r / 20, lx = r - 20 * ly;
            int gy = ty0 + ly - 2, gx = tx0 + lx - 2;
            bool in = ((unsigned)gy < HW) & ((unsigned)gx < HW);
            float vals[12];
#pragma unroll
            for (int c = 0; c < 12; ++c) vals[c] = 0.f;
            if (in) {
                const float* sp = src + (gy << 7) + gx;
#pragma unroll
                for (int c = 0; c < 12; ++c) vals[c] = sp[(size_t)c << 14];
            }
            v8h h0, h1;
#pragma unroll
            for (int c = 0; c < 8; ++c) h0[c] = (_Float16)vals[c];
#pragma unroll
            for (int c = 0; c < 4; ++c) h1[c] = (_Float16)vals[8 + c];
            h1[4] = (_Float16)((ch == 1 && in) ? 1.f : 0.f);  // ones channel
            h1[5] = h1[6] = h1[7] = (_Float16)0.f;
            *(v8h*)&s_in[r * 16]     = h0;
            *(v8h*)&s_in[r * 16 + 8] = h1;
        }
        __syncthreads();

        v8h bfA[5];
#pragma unroll
        for (int s = 0; s < 5; ++s)
            bfA[s] = *(const v8h*)&wh[((ch * 5 + s) * 64 + lane) * 8];

#pragma unroll
        for (int t = 0; t < 6; ++t) {
            int mt = wave + 4 * t;
            if (mt < 21) {
#pragma unroll
                for (int s = 0; s < 5; ++s) {
                    v8h a = *(v8h*)&s_in[pbase[t] + toff1[s]];
                    accA[t] = __builtin_amdgcn_mfma_f32_16x16x32_f16(
                                  a, bfA[s], accA[t], 0, 0, 0);
                }
            }
        }
    }

    // ---- write s_x (x zero-padded outside image) ----
    if (col < 8) {
#pragma unroll
        for (int t = 0; t < 6; ++t) {
            int mt = wave + 4 * t;
            if (mt < 21) {
#pragma unroll
                for (int r = 0; r < 4; ++r) {
                    int pa = mt * 16 + quad * 4 + r;
                    int py = pa / 18, px = pa - 18 * py;
                    bool ok = (pa < 324) &&
                              ((unsigned)(ty0 + py - 1) < HW) &&
                              ((unsigned)(tx0 + px - 1) < HW);
                    float v = ok ? accA[t][r] : 0.f;
                    s_x[pa * 8 + col] = (_Float16)v;
                }
            }
        }
    }
    __syncthreads();

    // ---- i2h: 16 M-tiles, 3 K-steps, 2 N-tiles ----
    int toff2[3];
#pragma unroll
    for (int s = 0; s < 3; ++s) {
        int t = s * 4 + quad;
        toff2[s] = (t < 9) ? ((t / 3) * 18 + (t % 3)) * 8 : 0;
    }
    v8h bfB[3][2];
#pragma unroll
    for (int s = 0; s < 3; ++s)
#pragma unroll
        for (int nt = 0; nt < 2; ++nt)
            bfB[s][nt] = *(const v8h*)&wh[WBF_OFF/2 + ((s*2 + nt)*64 + lane)*8];

    v4f acc0[4], acc1[4];
#pragma unroll
    for (int t = 0; t < 4; ++t) {
        acc0[t] = (v4f){0.f, 0.f, 0.f, 0.f};
        acc1[t] = (v4f){0.f, 0.f, 0.f, 0.f};
    }
#pragma unroll
    for (int t = 0; t < 4; ++t) {
        int mt = wave + 4 * t;
        int abase = (mt * 18 + col) * 8;
#pragma unroll
        for (int s = 0; s < 3; ++s) {
            v8h a = *(v8h*)&s_x[abase + toff2[s]];
            acc0[t] = __builtin_amdgcn_mfma_f32_16x16x32_f16(a, bfB[s][0], acc0[t], 0,0,0);
            acc1[t] = __builtin_amdgcn_mfma_f32_16x16x32_f16(a, bfB[s][1], acc1[t], 0,0,0);
        }
    }

    // ---- gates from C-frags (i_r: own col<8; i_u: col+8 via shfl; i_m: N1) ----
    const int c7 = lane & 7;
    const float g0v = fw[c7], g1v = fw[8 + c7], g2v = fw[16 + c7], g3v = fw[24 + c7];
#pragma unroll
    for (int t = 0; t < 4; ++t) {
        int mt = wave + 4 * t;
#pragma unroll
        for (int r = 0; r < 4; ++r) {
            float iu = __shfl_xor(acc0[t][r], 8, 64);
            if (col < 8) {
                float rr = 1.f / (1.f + __expf(-(acc0[t][r] + g0v)));
                float uu = 1.f / (1.f + __expf(-(iu + g1v)));
                float mm = acc1[t][r] + g2v + rr * g3v;
                mm = (mm >= 0.f) ? mm : 0.2f * mm;
                s_hc[(mt * 16 + quad * 4 + r) * 9 + c7] = (1.f - uu) * mm;
            }
        }
    }
    __syncthreads();

    // ---- conv_out (1x1, 8->12) per thread ----
    float h[8];
#pragma unroll
    for (int c = 0; c < 8; ++c) h[c] = s_hc[tid * 9 + c];
    const float* wout = fw + 32;
    const float* bout = fw + 128;
    const int oy = tid >> 4, ox = tid & 15;
    float* op = out + (((size_t)b * 12) << 14) + ((ty0 + oy) << 7) + (tx0 + ox);
#pragma unroll
    for (int t = 0; t < 12; ++t) {
        float o = bout[t];
#pragma unroll
        for (int c = 0; c < 8; ++c) o = fmaf(h[c], wout[t * 8 + c], o);
        op[(size_t)t << 14] = o;
    }
}

extern "C" void kernel_launch(void* const* d_in, const int* in_sizes, int n_in,
                              void* d_out, int out_size, void* d_ws, size_t ws_size,
                              hipStream_t stream) {
    (void)in_sizes; (void)n_in; (void)ws_size; (void)out_size;
    const float* radar = (const float*)d_in[0];
    const float* pred  = (const float*)d_in[1];
    const float* w_in  = (const float*)d_in[2];
    const float* b_in  = (const float*)d_in[3];
    const float* w_i2h = (const float*)d_in[4];
    const float* b_i2h = (const float*)d_in[5];
    // d_in[6..12] (flow branch, w_ret) are dead: h0 == 0.
    const float* b_ret = (const float*)d_in[13];
    const float* w_out = (const float*)d_in[14];
    const float* b_out = (const float*)d_in[15];

    prep<<<(N_PREP + 255) / 256, 256, 0, stream>>>(w_in, b_in, w_i2h, b_i2h,
                                                   b_ret, w_out, b_out, d_ws);

    dim3 grid(HW / 16, HW / 16, 32);
    radar2_mfma<<<grid, dim3(256), 0, stream>>>(radar, pred, d_ws, (float*)d_out);
}

// Round 7
// 140.452 us; speedup vs baseline: 1.8723x; 1.0451x over previous
//
#include <hip/hip_runtime.h>
#include <hip/hip_bf16.h>

// RadarSecondStageGenerator — MFMA fp16, round 6: staging instruction diet,
// LDS aliasing (5 blocks/CU), XCD-locality swizzle.
//
// h0 == 0 ⇒ flow/warp/w_ret branch dead; network = conv3x3(24->8) ->
// conv3x3(8->24) -> GRU gates (h2h == b_ret) -> conv1x1(8->12).
//
// conv_in im2col: M = 324 x-halo px (21 tiles), N = 8, K = 9 taps x 32 ch
//   (ch 0..11 radar, 12..23 pred, 24 = ones channel carrying b_in at the
//   center tap, 25..31 zero pad) -> 9 MFMA (16x16x32) per M-tile.
// i2h: M = 256 px (16 tiles), N = 24 (2 N-tiles), K = 12 taps x 8 ch (3 steps).
// Fragment layouts (HW-verified): A[m=lane&15][k=quad*8+j], C[row=quad*4+reg][col=lane&15].

typedef __fp16   h2f __attribute__((ext_vector_type(2)));   // cvt_pkrtz return type
typedef _Float16 v8h __attribute__((ext_vector_type(8)));
typedef float    v4f __attribute__((ext_vector_type(4)));

#define HW 128

#define WB_HOFF 4608     // half-index of i2h B-frags in ws
#define FLT_OFF 16384    // byte offset of float params in ws
#define N_PREP  7820     // 4608 + 3072 halfs, then 140 floats

__global__ __launch_bounds__(256)
void prep(const float* __restrict__ w_in,  const float* __restrict__ b_in,
          const float* __restrict__ w_i2h, const float* __restrict__ b_i2h,
          const float* __restrict__ b_ret, const float* __restrict__ w_out,
          const float* __restrict__ b_out, void* __restrict__ ws)
{
    int idx = blockIdx.x * 256 + threadIdx.x;
    _Float16* wh = (_Float16*)ws;
    float* fw = (float*)((char*)ws + FLT_OFF);
    if (idx < 4608) {                       // conv_in B-frags [s9][lane64][j8]
        int j = idx & 7, r = idx >> 3;
        int lane = r & 63, s = r >> 6;      // s = tap 0..8
        int quad = lane >> 4, n = lane & 15;
        int ch = quad * 8 + j;              // k within step = channel 0..31
        float v = 0.f;
        if (n < 8) {
            if (ch < 24)                 v = w_in[n*216 + ch*9 + s];
            else if (ch == 24 && s == 4) v = b_in[n];   // ones-channel bias
        }
        wh[idx] = (_Float16)v;
    } else if (idx < 7680) {                // i2h B-frags [s3][nt2][lane64][j8]
        int i2 = idx - 4608;
        int j = i2 & 7, r = i2 >> 3;
        int lane = r & 63; r >>= 6;
        int nt = r & 1, s = r >> 1;
        int quad = lane >> 4, n = lane & 15;
        int kk = s * 32 + quad * 8 + j;     // K: tap-major, 8 ch per tap
        int t = kk >> 3, m = kk & 7;        // tap 0..11 (9..11 pad)
        int o = nt * 16 + n;
        float v = (t < 9 && o < 24) ? w_i2h[o*72 + m*9 + t] : 0.f;
        wh[WB_HOFF + i2] = (_Float16)v;
    } else if (idx < N_PREP) {
        int j = idx - 7680;
        float v;
        if (j < 32) {                       // combined gate biases
            int c = j & 7, sel = j >> 3;
            v = (sel==0) ? b_i2h[c]    + b_ret[c]
              : (sel==1) ? b_i2h[8+c]  + b_ret[8+c]
              : (sel==2) ? b_i2h[16+c] : b_ret[16+c];
        } else if (j < 128) v = w_out[j-32];
        else                v = b_out[j-128];
        fw[j] = v;
    }
}

__global__ __launch_bounds__(256, 4)
void radar2_mfma(const float* __restrict__ radar,  // (32,12,128,128)
                 const float* __restrict__ pred,   // (32,12,128,128)
                 const void*  __restrict__ ws,
                 float* __restrict__ out)          // (32,12,128,128)
{
    // LDS pool: s_in [400][32] f16 (25600 B) | s_x [336][8] f16 (5376 B)
    // s_hc [256][9] f32 (9216 B) aliases s_in (dead after conv_in barrier).
    __shared__ __align__(16) char pool[25600 + 5376];
    _Float16* s_in = (_Float16*)pool;
    _Float16* s_x  = (_Float16*)(pool + 25600);
    float*    s_hc = (float*)pool;

    const _Float16* wh = (const _Float16*)ws;
    const float* fw = (const float*)((const char*)ws + FLT_OFF);

    const int tid  = threadIdx.x;
    const int lane = tid & 63;
    const int wave = tid >> 6;
    const int quad = lane >> 4;
    const int col  = lane & 15;

    // XCD-locality swizzle: id&7 = XCD (round-robin dispatch); each XCD's
    // 256-block stripe covers 4 whole batches -> halo reuse stays in one L2.
    const int id   = blockIdx.x;
    const int b    = (id & 7) * 4 + ((id >> 3) >> 6);
    const int tile = (id >> 3) & 63;
    const int ty0  = (tile >> 3) << 4;
    const int tx0  = (tile & 7) << 4;

    // conv_in B-frags (issue early, global, hidden under staging)
    v8h bfA[9];
#pragma unroll
    for (int s = 0; s < 9; ++s) bfA[s] = *(const v8h*)&wh[(s * 64 + lane) * 8];

    // ---- stage halo-2 patch, 25 live channels, channel-last ----
    const float* rb = radar + (((size_t)b * 12) << 14);
    const float* pb = pred  + (((size_t)b * 12) << 14);
#pragma unroll 1
    for (int rr = tid; rr < 400; rr += 256) {
        int ly = rr / 20, lx = rr - 20 * ly;
        int gy = ty0 + ly - 2, gx = tx0 + lx - 2;
        bool in = ((unsigned)gy < HW) & ((unsigned)gx < HW);
        int voff = (gy << 7) + gx;
        float v[26];
#pragma unroll
        for (int c = 0; c < 26; ++c) v[c] = 0.f;
        if (in) {
#pragma unroll
            for (int c = 0; c < 12; ++c) v[c]      = rb[((size_t)c << 14) + voff];
#pragma unroll
            for (int c = 0; c < 12; ++c) v[12 + c] = pb[((size_t)c << 14) + voff];
            v[24] = 1.f;
        }
        union { h2f h2[16]; v8h h8[4]; } u;
#pragma unroll
        for (int k = 0; k < 13; ++k)
            u.h2[k] = __builtin_amdgcn_cvt_pkrtz(v[2 * k], v[2 * k + 1]);
#pragma unroll
        for (int k = 13; k < 16; ++k) u.h2[k] = (h2f)0.f;
#pragma unroll
        for (int k = 0; k < 4; ++k) *(v8h*)&s_in[rr * 32 + 8 * k] = u.h8[k];
    }
    __syncthreads();

    // ---- conv_in: 21 M-tiles over 4 waves, 9 MFMA each ----
    int pbase[6];
#pragma unroll
    for (int t = 0; t < 6; ++t) {
        int p = (wave + 4 * t) * 16 + col; if (p > 323) p = 323;
        pbase[t] = ((p / 18) * 20 + (p % 18)) * 32 + quad * 8;
    }
    v4f accA[6];
#pragma unroll
    for (int t = 0; t < 6; ++t) accA[t] = (v4f){0.f, 0.f, 0.f, 0.f};
#pragma unroll
    for (int t = 0; t < 6; ++t) {
        if (wave + 4 * t < 21) {
#pragma unroll
            for (int s = 0; s < 9; ++s) {
                v8h a = *(const v8h*)&s_in[pbase[t] + ((s / 3) * 20 + (s % 3)) * 32];
                accA[t] = __builtin_amdgcn_mfma_f32_16x16x32_f16(a, bfA[s], accA[t], 0, 0, 0);
            }
        }
    }

    // ---- write s_x (x zero-padded outside the image) ----
    if (col < 8) {
#pragma unroll
        for (int t = 0; t < 6; ++t) {
            int mt = wave + 4 * t;
            if (mt < 21) {
#pragma unroll
                for (int r = 0; r < 4; ++r) {
                    int pa = mt * 16 + quad * 4 + r;
                    int py = pa / 18, px = pa - 18 * py;
                    bool ok = (pa < 324) &&
                              ((unsigned)(ty0 + py - 1) < HW) &&
                              ((unsigned)(tx0 + px - 1) < HW);
                    s_x[pa * 8 + col] = (_Float16)(ok ? accA[t][r] : 0.f);
                }
            }
        }
    }
    __syncthreads();

    // ---- i2h: 16 M-tiles, 3 K-steps, 2 N-tiles ----
    int toff2[3];
#pragma unroll
    for (int s = 0; s < 3; ++s) {
        int t = s * 4 + quad;
        toff2[s] = (t < 9) ? ((t / 3) * 18 + (t % 3)) * 8 : 0;
    }
    v8h bfB[3][2];
#pragma unroll
    for (int s = 0; s < 3; ++s)
#pragma unroll
        for (int nt = 0; nt < 2; ++nt)
            bfB[s][nt] = *(const v8h*)&wh[WB_HOFF + ((s * 2 + nt) * 64 + lane) * 8];

    v4f acc0[4], acc1[4];
#pragma unroll
    for (int t = 0; t < 4; ++t) {
        acc0[t] = (v4f){0.f, 0.f, 0.f, 0.f};
        acc1[t] = (v4f){0.f, 0.f, 0.f, 0.f};
    }
#pragma unroll
    for (int t = 0; t < 4; ++t) {
        int abase = ((wave + 4 * t) * 18 + col) * 8;
#pragma unroll
        for (int s = 0; s < 3; ++s) {
            v8h a = *(const v8h*)&s_x[abase + toff2[s]];
            acc0[t] = __builtin_amdgcn_mfma_f32_16x16x32_f16(a, bfB[s][0], acc0[t], 0, 0, 0);
            acc1[t] = __builtin_amdgcn_mfma_f32_16x16x32_f16(a, bfB[s][1], acc1[t], 0, 0, 0);
        }
    }

    // ---- gates from C-frags ----
    const int c7 = lane & 7;
    const float g0v = fw[c7], g1v = fw[8 + c7], g2v = fw[16 + c7], g3v = fw[24 + c7];
#pragma unroll
    for (int t = 0; t < 4; ++t) {
        int mt = wave + 4 * t;
#pragma unroll
        for (int r = 0; r < 4; ++r) {
            float iu = __shfl_xor(acc0[t][r], 8, 64);
            if (col < 8) {
                float rr = 1.f / (1.f + __expf(-(acc0[t][r] + g0v)));
                float uu = 1.f / (1.f + __expf(-(iu + g1v)));
                float mm = acc1[t][r] + g2v + rr * g3v;
                mm = (mm >= 0.f) ? mm : 0.2f * mm;
                s_hc[(mt * 16 + quad * 4 + r) * 9 + c7] = (1.f - uu) * mm;
            }
        }
    }
    __syncthreads();

    // ---- conv_out (1x1, 8->12) ----
    float h[8];
#pragma unroll
    for (int c = 0; c < 8; ++c) h[c] = s_hc[tid * 9 + c];
    const float* wout = fw + 32;
    const float* bout = fw + 128;
    const int oy = tid >> 4, ox = tid & 15;
    float* op = out + (((size_t)b * 12) << 14) + ((ty0 + oy) << 7) + (tx0 + ox);
#pragma unroll
    for (int t = 0; t < 12; ++t) {
        float o = bout[t];
#pragma unroll
        for (int c = 0; c < 8; ++c) o = fmaf(h[c], wout[t * 8 + c], o);
        op[(size_t)t << 14] = o;
    }
}

extern "C" void kernel_launch(void* const* d_in, const int* in_sizes, int n_in,
                              void* d_out, int out_size, void* d_ws, size_t ws_size,
                              hipStream_t stream) {
    (void)in_sizes; (void)n_in; (void)ws_size; (void)out_size;
    const float* radar = (const float*)d_in[0];
    const float* pred  = (const float*)d_in[1];
    const float* w_in  = (const float*)d_in[2];
    const float* b_in  = (const float*)d_in[3];
    const float* w_i2h = (const float*)d_in[4];
    const float* b_i2h = (const float*)d_in[5];
    // d_in[6..12] (flow branch, w_ret) are dead: h0 == 0.
    const float* b_ret = (const float*)d_in[13];
    const float* w_out = (const float*)d_in[14];
    const float* b_out = (const float*)d_in[15];

    prep<<<(N_PREP + 255) / 256, 256, 0, stream>>>(w_in, b_in, w_i2h, b_i2h,
                                                   b_ret, w_out, b_out, d_ws);

    radar2_mfma<<<dim3(2048), dim3(256), 0, stream>>>(radar, pred, d_ws, (float*)d_out);
}